// Round 4
// baseline (55.578 us; speedup 1.0000x reference)
//
#include <hip/hip_runtime.h>

#define N_ATOMS 512
#define N_PAIRS 130816            // 512*511/2
#define BATCH 128

typedef float f32x4 __attribute__((ext_vector_type(4)));

// AU2KCALMOLA / MAX_NRF
constexpr float SCALE = (float)(627.5095 * 0.529177 / 100.0);

// Block k (k = 0..255) of batch b handles rows i=k (length k) and
// i=511-k (length 511-k): exactly 511 pairs per block, perfectly balanced,
// no per-pair index inversion (no sqrt), contiguous anc/out runs.
__global__ __launch_bounds__(256) void coords_to_nrf_kernel(
    const float* __restrict__ coords,   // [B, 512, 3]
    const float* __restrict__ atom_nc,  // [B, N_PAIRS]
    float* __restrict__ out)            // [B, N_PAIRS]
{
    __shared__ f32x4 c4[N_ATOMS];       // 8 KiB, padded xyz_ per atom

    const int b = blockIdx.y;
    const int k = blockIdx.x;           // 0..255
    const int t = threadIdx.x;

    // Stage coords -> LDS as padded float4 (16B-aligned ds_read_b128 later).
    const float* cb = coords + (size_t)b * (N_ATOMS * 3);
    #pragma unroll
    for (int a = t; a < N_ATOMS; a += 256) {
        f32x4 v;
        v.x = cb[3 * a + 0];
        v.y = cb[3 * a + 1];
        v.z = cb[3 * a + 2];
        v.w = 0.0f;
        c4[a] = v;
    }
    __syncthreads();

    const int i1 = k;                   // row length k
    const int i2 = 511 - k;             // row length 511-k
    const int base1 = (i1 * (i1 - 1)) / 2;
    const int base2 = (i2 * (i2 - 1)) / 2;
    const f32x4 ci1 = c4[i1];           // broadcast reads, hoisted
    const f32x4 ci2 = c4[i2];

    const float* ab = atom_nc + (size_t)b * N_PAIRS;
    float*       ob = out     + (size_t)b * N_PAIRS;

    // 511 work items over 256 threads: exactly 2 predicated iterations.
    #pragma unroll
    for (int u = 0; u < 2; ++u) {
        const int idx = t + u * 256;
        if (idx < 511) {
            const bool first = idx < i1;
            const int  j = first ? idx : idx - i1;          // j < i for its row
            const int  p = (first ? base1 : base2) + j;
            const f32x4 ci = first ? ci1 : ci2;
            const f32x4 cj = c4[j];                          // lane-consecutive b128
            const float dx = ci.x - cj.x;
            const float dy = ci.y - cj.y;
            const float dz = ci.z - cj.z;
            const float d2 = dx * dx + dy * dy + dz * dz;
            const float a  = __builtin_nontemporal_load(&ab[p]);
            __builtin_nontemporal_store(a * (SCALE / d2), &ob[p]);
        }
    }
}

extern "C" void kernel_launch(void* const* d_in, const int* in_sizes, int n_in,
                              void* d_out, int out_size, void* d_ws, size_t ws_size,
                              hipStream_t stream) {
    const float* coords  = (const float*)d_in[0];  // [128, 512, 3] f32
    const float* atom_nc = (const float*)d_in[1];  // [128, 130816] f32
    float* out = (float*)d_out;                    // [128, 130816] f32

    dim3 block(256);
    dim3 grid(256, BATCH);                         // 256 row-pair blocks x 128 batches
    coords_to_nrf_kernel<<<grid, block, 0, stream>>>(coords, atom_nc, out);
}

// Round 5
// 42.295 us; speedup vs baseline: 1.3140x; 1.3140x over previous
//
#include <hip/hip_runtime.h>

#define N_ATOMS 512
#define N_PAIRS 130816            // 512*511/2
#define BATCH 128

typedef float f32x4 __attribute__((ext_vector_type(4)));

// AU2KCALMOLA / MAX_NRF
constexpr float SCALE = (float)(627.5095 * 0.529177 / 100.0);

// Block blk (0..63) of batch b handles 4 balanced row-pairs:
//   for m in 0..3: k = 4*blk + m, rows i1=k (len k) and i2=511-k (len 511-k)
//   -> exactly 4*511 = 2044 pairs per block, perfectly balanced.
// i is (nearly) wave-uniform -> no per-pair index inversion (no sqrt).
// j is lane-consecutive -> LDS reads at float-stride 3: bank stride 3,
// coprime with 32 -> conflict-free. anc/out runs are contiguous -> coalesced.
__global__ __launch_bounds__(256) void coords_to_nrf_kernel(
    const float* __restrict__ coords,   // [B, 512, 3]
    const float* __restrict__ atom_nc,  // [B, N_PAIRS]
    float* __restrict__ out)            // [B, N_PAIRS]
{
    __shared__ float c[N_ATOMS * 3];    // 6144 B, linear xyzxyz...

    const int b   = blockIdx.y;
    const int blk = blockIdx.x;         // 0..63
    const int t   = threadIdx.x;

    // Stage coords -> LDS with coalesced f32x4 loads (384 vec4s).
    {
        const f32x4* src = reinterpret_cast<const f32x4*>(coords + (size_t)b * (N_ATOMS * 3));
        f32x4* dst = reinterpret_cast<f32x4*>(c);
        for (int u = t; u < (N_ATOMS * 3) / 4; u += 256) dst[u] = src[u];
    }
    __syncthreads();

    const float* ab = atom_nc + (size_t)b * N_PAIRS;
    float*       ob = out     + (size_t)b * N_PAIRS;

    #pragma unroll
    for (int m = 0; m < 4; ++m) {
        const int k  = blk * 4 + m;         // 0..255
        const int i1 = k;                   // row length k   (empty when k==0)
        const int i2 = 511 - k;             // row length 511-k
        const int base1 = (i1 * (i1 - 1)) / 2;
        const int base2 = (i2 * (i2 - 1)) / 2;
        // Hoisted uniform row-atom reads (LDS broadcast).
        const float xi1 = c[3 * i1], yi1 = c[3 * i1 + 1], zi1 = c[3 * i1 + 2];
        const float xi2 = c[3 * i2], yi2 = c[3 * i2 + 1], zi2 = c[3 * i2 + 2];

        #pragma unroll
        for (int u = 0; u < 2; ++u) {
            const int idx = u * 256 + t;    // 0..511 over the virtual 511-row
            if (idx < 511) {
                const bool first = idx < i1;
                const int  j = first ? idx : idx - i1;      // j < row length
                const int  p = (first ? base1 : base2) + j;
                const float xi = first ? xi1 : xi2;
                const float yi = first ? yi1 : yi2;
                const float zi = first ? zi1 : zi2;
                // Lane-consecutive j -> stride-3 floats -> conflict-free.
                const float xj = c[3 * j], yj = c[3 * j + 1], zj = c[3 * j + 2];
                const float dx = xi - xj, dy = yi - yj, dz = zi - zj;
                const float d2 = dx * dx + dy * dy + dz * dz;
                const float a  = __builtin_nontemporal_load(&ab[p]);
                __builtin_nontemporal_store(a * (SCALE / d2), &ob[p]);
            }
        }
    }
}

extern "C" void kernel_launch(void* const* d_in, const int* in_sizes, int n_in,
                              void* d_out, int out_size, void* d_ws, size_t ws_size,
                              hipStream_t stream) {
    const float* coords  = (const float*)d_in[0];  // [128, 512, 3] f32
    const float* atom_nc = (const float*)d_in[1];  // [128, 130816] f32
    float* out = (float*)d_out;                    // [128, 130816] f32

    dim3 block(256);
    dim3 grid(64, BATCH);                          // 64 blocks x 128 batches
    coords_to_nrf_kernel<<<grid, block, 0, stream>>>(coords, atom_nc, out);
}

// Round 6
// 27.961 us; speedup vs baseline: 1.9877x; 1.5127x over previous
//
#include <hip/hip_runtime.h>

#define N_ATOMS 512
#define N_PAIRS 130816            // 512*511/2
#define BATCH 128

typedef float f32x4 __attribute__((ext_vector_type(4)));

// AU2KCALMOLA / MAX_NRF
constexpr float SCALE = (float)(627.5095 * 0.529177 / 100.0);

// Block blk (0..63) of batch b handles 4 balanced row-pairs:
//   k = 4*blk+m -> rows i1=k (len k) and i2=511-k (len 511-k), 511 pairs each.
// Phase-split: all global loads + LDS reads issued first (8-deep MLP),
// then compute (v_rcp, no IEEE div), then stores.
__global__ __launch_bounds__(256) void coords_to_nrf_kernel(
    const float* __restrict__ coords,   // [B, 512, 3]
    const float* __restrict__ atom_nc,  // [B, N_PAIRS]
    float* __restrict__ out)            // [B, N_PAIRS]
{
    __shared__ float c[N_ATOMS * 3];    // 6144 B, linear xyzxyz...

    const int b   = blockIdx.y;
    const int blk = blockIdx.x;         // 0..63
    const int t   = threadIdx.x;

    // Stage coords -> LDS with coalesced f32x4 loads.
    {
        const f32x4* src = reinterpret_cast<const f32x4*>(coords + (size_t)b * (N_ATOMS * 3));
        f32x4* dst = reinterpret_cast<f32x4*>(c);
        for (int u = t; u < (N_ATOMS * 3) / 4; u += 256) dst[u] = src[u];
    }
    __syncthreads();

    const float* ab = atom_nc + (size_t)b * N_PAIRS;
    float*       ob = out     + (size_t)b * N_PAIRS;

    float a[8], xj[8], yj[8], zj[8], xi[8], yi[8], zi[8];
    int   pp[8];

    // Phase 1: indices + all memory issues (8 global loads, 24 LDS reads).
    #pragma unroll
    for (int m = 0; m < 4; ++m) {
        const int k  = blk * 4 + m;
        const int i1 = k;                   // row length k
        const int i2 = 511 - k;             // row length 511-k
        const int base1 = (i1 * (i1 - 1)) / 2;
        const int base2 = (i2 * (i2 - 1)) / 2;
        const float xi1 = c[3 * i1], yi1 = c[3 * i1 + 1], zi1 = c[3 * i1 + 2];
        const float xi2 = c[3 * i2], yi2 = c[3 * i2 + 1], zi2 = c[3 * i2 + 2];

        #pragma unroll
        for (int u = 0; u < 2; ++u) {
            const int r = m * 2 + u;
            // idx 511 (u==1, t==255) clamps to 510: duplicates lane 254's
            // pair with an identical value -> benign double-store.
            const int idx = min(u * 256 + t, 510);
            const bool first = idx < i1;
            const int  j = first ? idx : idx - i1;          // j < row length
            pp[r] = (first ? base1 : base2) + j;
            xi[r] = first ? xi1 : xi2;
            yi[r] = first ? yi1 : yi2;
            zi[r] = first ? zi1 : zi2;
            // Lane-consecutive j -> stride-3 floats -> conflict-free LDS.
            xj[r] = c[3 * j];
            yj[r] = c[3 * j + 1];
            zj[r] = c[3 * j + 2];
            a[r]  = ab[pp[r]];
        }
    }

    // Phase 2: compute + streaming stores.
    #pragma unroll
    for (int r = 0; r < 8; ++r) {
        const float dx = xi[r] - xj[r];
        const float dy = yi[r] - yj[r];
        const float dz = zi[r] - zj[r];
        const float d2 = dx * dx + dy * dy + dz * dz;
        const float res = a[r] * SCALE * __builtin_amdgcn_rcpf(d2);
        __builtin_nontemporal_store(res, &ob[pp[r]]);
    }
}

extern "C" void kernel_launch(void* const* d_in, const int* in_sizes, int n_in,
                              void* d_out, int out_size, void* d_ws, size_t ws_size,
                              hipStream_t stream) {
    const float* coords  = (const float*)d_in[0];  // [128, 512, 3] f32
    const float* atom_nc = (const float*)d_in[1];  // [128, 130816] f32
    float* out = (float*)d_out;                    // [128, 130816] f32

    dim3 block(256);
    dim3 grid(64, BATCH);                          // 64 blocks x 128 batches
    coords_to_nrf_kernel<<<grid, block, 0, stream>>>(coords, atom_nc, out);
}